// Round 12
// baseline (353.139 us; speedup 1.0000x reference)
//
#include <hip/hip_runtime.h>

#define B_   128
#define L_   196
#define ENC_ 2048
#define DEC_ 512
#define ATT_ 512
#define M_   (B_ * L_)   // 25088

typedef _Float16 f16x4 __attribute__((ext_vector_type(4)));
typedef _Float16 f16x8 __attribute__((ext_vector_type(8)));
typedef __fp16   h16x2 __attribute__((ext_vector_type(2)));
typedef float    f32x4 __attribute__((ext_vector_type(4)));

// ---------------- ws layout ----------------
// [0,          262144)   dec_map  f32 [128][512]
// [262144,    2359296)   WeTs     f16 tiled: [ntile=4][kt=64][k8=4][row=128] x f16x8 unit
// [2359296,   2760704)   partial  f32 [4][25088]

// We [2048][512] fp32 -> WeTs tiled-f16. Unit (nt,kt,k8,row) holds
// We[kt*32+k8*8+j][nt*128+row] for j=0..7.
__global__ void wets_kernel(const float* __restrict__ We, _Float16* __restrict__ WeTs) {
    int u = blockIdx.x * 256 + threadIdx.x;     // 131072 units
    int row = u & 127;
    int k8  = (u >> 7) & 3;
    int kt  = (u >> 9) & 63;
    int nt  = u >> 15;
    int n  = nt * 128 + row;
    int k0 = kt * 32 + k8 * 8;
    f16x8 h;
#pragma unroll
    for (int j = 0; j < 8; ++j) h[j] = (_Float16)We[(k0 + j) * ATT_ + n];
    *reinterpret_cast<f16x8*>(WeTs + (size_t)u * 8) = h;
}

// dec_map[b][a] = decoder_hidden[b] . Wd[:,a] + bd[a]
__global__ void decmap_kernel(const float* __restrict__ dh, const float* __restrict__ Wd,
                              const float* __restrict__ bd, float* __restrict__ dec) {
    int b = blockIdx.x;       // 128
    int a = threadIdx.x;      // 512
    float acc = bd[a];
    const float* dhp = dh + b * DEC_;
#pragma unroll 8
    for (int k = 0; k < DEC_; ++k) acc += dhp[k] * Wd[k * ATT_ + a];
    dec[b * ATT_ + a] = acc;
}

// Fused GEMM, BARRIER-FREE K-loop: no LDS staging at all. Each wave loads its
// A fragments directly from global (8 consecutive fp32 per lane per mi = 2x
// float4, full 128B-line use across lg) and converts in-register; B fragments
// come from the pre-tiled WeTs (L2-resident). Waves are fully independent ->
// TLP (12 waves/CU) + compiler software-pipelining with counted vmcnt hides
// latency; no barrier ever drains the load queue. (R8-R11: the 2-barrier/step
// LDS structure plateaued at ~2400cy/step, latency-bound at 1 TB/s.)
// launch_bounds(256,3): unified VGPR/AGPR file; 64-reg f32 accumulator + ~90
// arch regs need the 170 cap. (256,4) caps at 128 -> catastrophic spill
// (R7: 280MB, R10: 957MB scratch). DO NOT raise.
__global__ __launch_bounds__(256, 3)
void gemm_score_kernel(const float* __restrict__ enc,
                       const _Float16* __restrict__ WeTs,
                       const float* __restrict__ be,
                       const float* __restrict__ wa,
                       const float* __restrict__ dec,
                       float* __restrict__ partial) {
    __shared__ float red[2][128];

    // XCD-chunked swizzle: 4 ntile-siblings of one mtile stay on one XCD.
    int bid = blockIdx.x;
    int sid = (bid & 7) * 98 + (bid >> 3);           // bijective on [0,784)
    int mtile = sid >> 2;                            // 0..195
    int ntile = sid & 3;                             // 0..3

    int tid  = threadIdx.x;
    int lane = tid & 63, wid = tid >> 6;
    int wm = wid >> 1, wn = wid & 1;                 // 2x2 waves of 64x64
    int l15 = lane & 15, lg = lane >> 4;

    // A fragment pointers: row rb+mi*16+l15, col base lg*8 (stride 32/kt)
    int rb = mtile * 128 + wm * 64;
    const float* pA0 = enc + (size_t)(rb + 0 * 16 + l15) * ENC_ + lg * 8;
    const float* pA1 = enc + (size_t)(rb + 1 * 16 + l15) * ENC_ + lg * 8;
    const float* pA2 = enc + (size_t)(rb + 2 * 16 + l15) * ENC_ + lg * 8;
    const float* pA3 = enc + (size_t)(rb + 3 * 16 + l15) * ENC_ + lg * 8;

    // B fragment source: WeTs unit (ntile, kt, k8=lg, row=wn*64+ni*16+l15)
    const _Float16* bfr = WeTs +
        ((size_t)ntile * 64 * 4 * 128 + (size_t)lg * 128 + wn * 64 + l15) * 8;
    // per-kt stride in halves: 4*128*8 = 4096

    f32x4 acc[4][4];
#pragma unroll
    for (int mi = 0; mi < 4; ++mi)
#pragma unroll
        for (int ni = 0; ni < 4; ++ni) acc[mi][ni] = (f32x4){0.f, 0.f, 0.f, 0.f};

#pragma unroll 2
    for (int kt = 0; kt < 64; ++kt) {
        f16x8 af[4], bf[4];
        {
            float4 lo, hi;
            union { h16x2 h2[4]; f16x8 h8; } cv;
            lo = *reinterpret_cast<const float4*>(pA0 + kt * 32);
            hi = *reinterpret_cast<const float4*>(pA0 + kt * 32 + 4);
            cv.h2[0] = __builtin_amdgcn_cvt_pkrtz(lo.x, lo.y);
            cv.h2[1] = __builtin_amdgcn_cvt_pkrtz(lo.z, lo.w);
            cv.h2[2] = __builtin_amdgcn_cvt_pkrtz(hi.x, hi.y);
            cv.h2[3] = __builtin_amdgcn_cvt_pkrtz(hi.z, hi.w);
            af[0] = cv.h8;
            lo = *reinterpret_cast<const float4*>(pA1 + kt * 32);
            hi = *reinterpret_cast<const float4*>(pA1 + kt * 32 + 4);
            cv.h2[0] = __builtin_amdgcn_cvt_pkrtz(lo.x, lo.y);
            cv.h2[1] = __builtin_amdgcn_cvt_pkrtz(lo.z, lo.w);
            cv.h2[2] = __builtin_amdgcn_cvt_pkrtz(hi.x, hi.y);
            cv.h2[3] = __builtin_amdgcn_cvt_pkrtz(hi.z, hi.w);
            af[1] = cv.h8;
            lo = *reinterpret_cast<const float4*>(pA2 + kt * 32);
            hi = *reinterpret_cast<const float4*>(pA2 + kt * 32 + 4);
            cv.h2[0] = __builtin_amdgcn_cvt_pkrtz(lo.x, lo.y);
            cv.h2[1] = __builtin_amdgcn_cvt_pkrtz(lo.z, lo.w);
            cv.h2[2] = __builtin_amdgcn_cvt_pkrtz(hi.x, hi.y);
            cv.h2[3] = __builtin_amdgcn_cvt_pkrtz(hi.z, hi.w);
            af[2] = cv.h8;
            lo = *reinterpret_cast<const float4*>(pA3 + kt * 32);
            hi = *reinterpret_cast<const float4*>(pA3 + kt * 32 + 4);
            cv.h2[0] = __builtin_amdgcn_cvt_pkrtz(lo.x, lo.y);
            cv.h2[1] = __builtin_amdgcn_cvt_pkrtz(lo.z, lo.w);
            cv.h2[2] = __builtin_amdgcn_cvt_pkrtz(hi.x, hi.y);
            cv.h2[3] = __builtin_amdgcn_cvt_pkrtz(hi.z, hi.w);
            af[3] = cv.h8;
        }
        {
            const _Float16* s = bfr + (size_t)kt * 4096;
#pragma unroll
            for (int ni = 0; ni < 4; ++ni)
                bf[ni] = *reinterpret_cast<const f16x8*>(s + ni * 16 * 8);
        }
#pragma unroll
        for (int mi = 0; mi < 4; ++mi)
#pragma unroll
            for (int ni = 0; ni < 4; ++ni)
                acc[mi][ni] = __builtin_amdgcn_mfma_f32_16x16x32_f16(
                    af[mi], bf[ni], acc[mi][ni], 0, 0, 0);
    }

    // Epilogue: x = acc + be[n] + dec[b][n]; t = tanh(x); rowsum += t*wa[n]
    float rsum[4][4];
#pragma unroll
    for (int mi = 0; mi < 4; ++mi)
#pragma unroll
        for (int j = 0; j < 4; ++j) rsum[mi][j] = 0.f;

    int nb = ntile * 128 + wn * 64;
#pragma unroll
    for (int ni = 0; ni < 4; ++ni) {
        int n = nb + ni * 16 + l15;
        float wav = wa[n];
        float bev = be[n];
#pragma unroll
        for (int mi = 0; mi < 4; ++mi) {
#pragma unroll
            for (int j = 0; j < 4; ++j) {
                int row = rb + mi * 16 + lg * 4 + j;    // C/D: col=lane&15, row=(lane>>4)*4+reg
                int b = row / L_;
                float x = acc[mi][ni][j] + bev + dec[b * ATT_ + n];
                float e = __expf(2.0f * x);
                float t = 1.0f - 2.0f / (e + 1.0f);     // tanh(x), inf-safe
                rsum[mi][j] += t * wav;
            }
        }
    }
#pragma unroll
    for (int mi = 0; mi < 4; ++mi) {
#pragma unroll
        for (int j = 0; j < 4; ++j) {
            float v = rsum[mi][j];
            v += __shfl_xor(v, 1);
            v += __shfl_xor(v, 2);
            v += __shfl_xor(v, 4);
            v += __shfl_xor(v, 8);
            if (l15 == 0) red[wn][wm * 64 + mi * 16 + lg * 4 + j] = v;
        }
    }
    __syncthreads();
    if (tid < 128)
        partial[(size_t)ntile * M_ + mtile * 128 + tid] = red[0][tid] + red[1][tid];
}

// softmax over L per batch row. ba cancels in softmax -> skipped.
__global__ void softmax_kernel(const float* __restrict__ partial, float* __restrict__ alphas) {
    int b = blockIdx.x, t = threadIdx.x;     // 128 blocks x 256 threads
    int lane = t & 63, wid = t >> 6;
    __shared__ float red[4];
    float s = 0.f, val = -1e30f;
    if (t < L_) {
        int r = b * L_ + t;
        s = partial[r] + partial[M_ + r] + partial[2 * M_ + r] + partial[3 * M_ + r];
        val = s;
    }
    float m = val;
#pragma unroll
    for (int off = 1; off < 64; off <<= 1) m = fmaxf(m, __shfl_xor(m, off));
    if (lane == 0) red[wid] = m;
    __syncthreads();
    m = fmaxf(fmaxf(red[0], red[1]), fmaxf(red[2], red[3]));
    float e = (t < L_) ? __expf(s - m) : 0.f;
    float sum = e;
#pragma unroll
    for (int off = 1; off < 64; off <<= 1) sum += __shfl_xor(sum, off);
    __syncthreads();
    if (lane == 0) red[wid] = sum;
    __syncthreads();
    sum = red[0] + red[1] + red[2] + red[3];
    if (t < L_) alphas[b * L_ + t] = e / sum;
}

// context[b][e] = sum_l alphas[b][l] * enc[b][l][e]   (memory-bound pass)
__global__ void context_kernel(const float* __restrict__ enc, const float* __restrict__ alphas,
                               float* __restrict__ ctx) {
    int b = blockIdx.x >> 2;                  // 128 b x 4 e-chunks = 512 blocks
    int ec = blockIdx.x & 3;
    int e = ec * 512 + threadIdx.x * 2;
    const float* ep = enc + (size_t)b * L_ * ENC_ + e;
    const float* ap = alphas + b * L_;
    float ax = 0.f, ay = 0.f;
#pragma unroll 4
    for (int l = 0; l < L_; ++l) {
        float a = ap[l];
        float2 v = *reinterpret_cast<const float2*>(ep + (size_t)l * ENC_);
        ax += a * v.x;
        ay += a * v.y;
    }
    float2 r; r.x = ax; r.y = ay;
    *reinterpret_cast<float2*>(&ctx[b * ENC_ + e]) = r;
}

extern "C" void kernel_launch(void* const* d_in, const int* in_sizes, int n_in,
                              void* d_out, int out_size, void* d_ws, size_t ws_size,
                              hipStream_t stream) {
    const float* enc = (const float*)d_in[0];
    const float* dh  = (const float*)d_in[1];
    const float* We  = (const float*)d_in[2];
    const float* be  = (const float*)d_in[3];
    const float* Wd  = (const float*)d_in[4];
    const float* bd  = (const float*)d_in[5];
    const float* wa  = (const float*)d_in[6];
    // d_in[7] = ba: shifts all scores equally -> cancels in softmax, unused.

    float* out    = (float*)d_out;
    float* ctx    = out;               // [128][2048]
    float* alphas = out + B_ * ENC_;   // [128][196]

    char* ws = (char*)d_ws;
    float*    dec     = (float*)ws;                            // 256 KiB
    _Float16* WeTs    = (_Float16*)(ws + 262144);              // 2 MiB
    float*    partial = (float*)(ws + 262144 + 2097152);       // 392 KiB

    hipLaunchKernelGGL(wets_kernel,       dim3(512),  dim3(256), 0, stream, We, WeTs);
    hipLaunchKernelGGL(decmap_kernel,     dim3(128),  dim3(512), 0, stream, dh, Wd, bd, dec);
    hipLaunchKernelGGL(gemm_score_kernel, dim3(784),  dim3(256), 0, stream, enc, WeTs, be, wa, dec, partial);
    hipLaunchKernelGGL(softmax_kernel,    dim3(128),  dim3(256), 0, stream, partial, alphas);
    hipLaunchKernelGGL(context_kernel,    dim3(512),  dim3(256), 0, stream, enc, alphas, ctx);
}

// Round 13
// 163.686 us; speedup vs baseline: 2.1574x; 2.1574x over previous
//
#include <hip/hip_runtime.h>

#define B_   128
#define L_   196
#define ENC_ 2048
#define DEC_ 512
#define ATT_ 512
#define M_   (B_ * L_)   // 25088

typedef _Float16 f16x4 __attribute__((ext_vector_type(4)));
typedef _Float16 f16x8 __attribute__((ext_vector_type(8)));
typedef __fp16   h16x2 __attribute__((ext_vector_type(2)));
typedef float    f32x4 __attribute__((ext_vector_type(4)));

// Raw barrier: order LDS ops (lgkmcnt) but do NOT drain vmcnt -> global
// prefetches stay in flight across the barrier.
#define FENCE_LDS_BARRIER()                                        \
    do {                                                           \
        asm volatile("s_waitcnt lgkmcnt(0)" ::: "memory");         \
        __builtin_amdgcn_s_barrier();                              \
        __builtin_amdgcn_sched_barrier(0);                         \
    } while (0)

// ---------------- ws layout ----------------
// [0,          262144)   dec_map  f32 [128][512]
// [262144,    2359296)   WeTs     f16 tiled: [ntile=4][kt=64][k8=4][row=128] x f16x8 unit
// [2359296,   2760704)   partial  f32 [4][25088]

// We [2048][512] fp32 -> WeTs tiled-f16. Unit (nt,kt,k8,row) holds
// We[kt*32+k8*8+j][nt*128+row] for j=0..7.
__global__ void wets_kernel(const float* __restrict__ We, _Float16* __restrict__ WeTs) {
    int u = blockIdx.x * 256 + threadIdx.x;     // 131072 units
    int row = u & 127;
    int k8  = (u >> 7) & 3;
    int kt  = (u >> 9) & 63;
    int nt  = u >> 15;
    int n  = nt * 128 + row;
    int k0 = kt * 32 + k8 * 8;
    f16x8 h;
#pragma unroll
    for (int j = 0; j < 8; ++j) h[j] = (_Float16)We[(k0 + j) * ATT_ + n];
    *reinterpret_cast<f16x8*>(WeTs + (size_t)u * 8) = h;
}

// dec_map[b][a] = decoder_hidden[b] . Wd[:,a] + bd[a]
__global__ void decmap_kernel(const float* __restrict__ dh, const float* __restrict__ Wd,
                              const float* __restrict__ bd, float* __restrict__ dec) {
    int b = blockIdx.x;       // 128
    int a = threadIdx.x;      // 512
    float acc = bd[a];
    const float* dhp = dh + b * DEC_;
#pragma unroll 8
    for (int k = 0; k < DEC_; ++k) acc += dhp[k] * Wd[k * ATT_ + a];
    dec[b * ATT_ + a] = acc;
}

// Fused GEMM: 128x128 tile, BK=32. 3-DEEP A pipeline: 3 static register sets
// (areg0/1/2) + 3 rotating LDS buffers; loadA issued 3 phases ahead ->
// ds_write's vm-wait has ~2 phases (>HBM latency) of slack. B direct
// global(L2)->reg 2-deep (bf0/bf1). lgkm-only barriers (no vmcnt drain).
// 6-phase manual unroll keeps all set/buf indices compile-time (rule #20).
// launch_bounds(256,3): unified VGPR/AGPR file; 64 acc + ~90 arch needs the
// 170 cap. (256,4) caps at 128 -> catastrophic spill (R7/R10). DO NOT raise.
__global__ __launch_bounds__(256, 3)
void gemm_score_kernel(const float* __restrict__ enc,
                       const _Float16* __restrict__ WeTs,
                       const float* __restrict__ be,
                       const float* __restrict__ wa,
                       const float* __restrict__ dec,
                       float* __restrict__ partial) {
    __shared__ _Float16 smem[3][4096];   // A: [buf][(k8*128+row)*8], 8KB each
    __shared__ float red[2][128];

    // XCD-chunked swizzle: 4 ntile-siblings of one mtile stay on one XCD.
    int bid = blockIdx.x;
    int sid = (bid & 7) * 98 + (bid >> 3);           // bijective on [0,784)
    int mtile = sid >> 2;                            // 0..195
    int ntile = sid & 3;                             // 0..3

    int tid  = threadIdx.x;
    int lane = tid & 63, wid = tid >> 6;
    int wm = wid >> 1, wn = wid & 1;                 // 2x2 waves of 64x64
    int l15 = lane & 15, lg = lane >> 4;

    // A staging: thread -> (row = tid>>2 (+64), c8 = tid&3)
    int arowi = tid >> 2;                            // 0..63
    int ac8   = tid & 3;
    const float* agA = enc + (size_t)(mtile * 128 + arowi) * ENC_ + ac8 * 8;
    const float* agB = agA + (size_t)64 * ENC_;
    int wa0 = (ac8 * 128 + (arowi ^ (2 * ac8))) * 8;   // swizzled A unit
    int wa1 = wa0 + 64 * 8;

    // B fragment source: WeTs unit (ntile, kt, k8=lg, row=wn*64+ni*16+l15)
    const _Float16* bfr = WeTs +
        ((size_t)ntile * 64 * 4 * 128 + (size_t)lg * 128 + wn * 64 + l15) * 8;
    // per-kt stride in halves: 4*128*8 = 4096

    // A frag read half-offsets
    int afo = (lg * 128 + wm * 64 + (l15 ^ (2 * lg))) * 8;   // A swizzled

    // staging register sets — statically named (rule #20)
    float4 areg0[4], areg1[4], areg2[4];
    f16x8  bf0[4], bf1[4];

    f32x4 acc[4][4];
#pragma unroll
    for (int mi = 0; mi < 4; ++mi)
#pragma unroll
        for (int ni = 0; ni < 4; ++ni) acc[mi][ni] = (f32x4){0.f, 0.f, 0.f, 0.f};

#define DEF_LOADA(S)                                                     \
    auto loadA##S = [&](int kt) {                                        \
        const float* a0 = agA + kt * 32;                                 \
        const float* a1 = agB + kt * 32;                                 \
        areg##S[0] = *reinterpret_cast<const float4*>(a0);               \
        areg##S[1] = *reinterpret_cast<const float4*>(a0 + 4);           \
        areg##S[2] = *reinterpret_cast<const float4*>(a1);               \
        areg##S[3] = *reinterpret_cast<const float4*>(a1 + 4);           \
    }
    DEF_LOADA(0); DEF_LOADA(1); DEF_LOADA(2);
#undef DEF_LOADA

#define DEF_LOADB(S)                                                     \
    auto loadB##S = [&](int kt) {                                        \
        const _Float16* s = bfr + (size_t)kt * 4096;                     \
        bf##S[0] = *reinterpret_cast<const f16x8*>(s + 0 * 128);         \
        bf##S[1] = *reinterpret_cast<const f16x8*>(s + 16 * 8);          \
        bf##S[2] = *reinterpret_cast<const f16x8*>(s + 32 * 8);          \
        bf##S[3] = *reinterpret_cast<const f16x8*>(s + 48 * 8);          \
    }
    DEF_LOADB(0); DEF_LOADB(1);
#undef DEF_LOADB

#define DEF_WRITEA(S)                                                    \
    auto writeA##S = [&](int buf) {                                      \
        _Float16* As = smem[buf];                                        \
        union { h16x2 h2[4]; f16x8 h8; } cv;                             \
        cv.h2[0] = __builtin_amdgcn_cvt_pkrtz(areg##S[0].x, areg##S[0].y); \
        cv.h2[1] = __builtin_amdgcn_cvt_pkrtz(areg##S[0].z, areg##S[0].w); \
        cv.h2[2] = __builtin_amdgcn_cvt_pkrtz(areg##S[1].x, areg##S[1].y); \
        cv.h2[3] = __builtin_amdgcn_cvt_pkrtz(areg##S[1].z, areg##S[1].w); \
        *reinterpret_cast<f16x8*>(As + wa0) = cv.h8;                     \
        cv.h2[0] = __builtin_amdgcn_cvt_pkrtz(areg##S[2].x, areg##S[2].y); \
        cv.h2[1] = __builtin_amdgcn_cvt_pkrtz(areg##S[2].z, areg##S[2].w); \
        cv.h2[2] = __builtin_amdgcn_cvt_pkrtz(areg##S[3].x, areg##S[3].y); \
        cv.h2[3] = __builtin_amdgcn_cvt_pkrtz(areg##S[3].z, areg##S[3].w); \
        *reinterpret_cast<f16x8*>(As + wa1) = cv.h8;                     \
    }
    DEF_WRITEA(0); DEF_WRITEA(1); DEF_WRITEA(2);
#undef DEF_WRITEA

    auto compute = [&](const _Float16* As, const f16x8* bf) {
        f16x8 af[4];
#pragma unroll
        for (int mi = 0; mi < 4; ++mi)
            af[mi] = *reinterpret_cast<const f16x8*>(As + afo + mi * 128);
        __builtin_amdgcn_s_setprio(1);
#pragma unroll
        for (int mi = 0; mi < 4; ++mi)
#pragma unroll
            for (int ni = 0; ni < 4; ++ni)
                acc[mi][ni] = __builtin_amdgcn_mfma_f32_16x16x32_f16(
                    af[mi], bf[ni], acc[mi][ni], 0, 0, 0);
        __builtin_amdgcn_s_setprio(0);
    };

    // Phase kt: loadA set kt%3 <- tile kt+3 (clamped); loadB set (kt+1)&1 <-
    // tile kt+1; ds_write set (kt+1)%3 -> buf (kt+1)%3 (vm-slack 2 phases);
    // barrier; compute buf kt%3 with B set kt&1.
#define PHASE(KT, S, WS, BS, CBS, RBUF, WBUF)                            \
    do {                                                                 \
        int ka = (KT) + 3 < 64 ? (KT) + 3 : 63;                          \
        int kb = (KT) + 1 < 64 ? (KT) + 1 : 63;                          \
        loadA##S(ka);                                                    \
        loadB##BS(kb);                                                   \
        writeA##WS(WBUF);                                                \
        FENCE_LDS_BARRIER();                                             \
        compute(smem[RBUF], bf##CBS);                                    \
    } while (0)

    // prologue: tiles 0,1,2 -> sets 0,1,2; B tile0 -> bf0; tile0 -> buf0
    loadA0(0);
    loadA1(1);
    loadA2(2);
    loadB0(0);
    writeA0(0);
    FENCE_LDS_BARRIER();

    for (int kt6 = 0; kt6 < 10; ++kt6) {
        int kt = kt6 * 6;
        PHASE(kt + 0, 0, 1, 1, 0, 0, 1);
        PHASE(kt + 1, 1, 2, 0, 1, 1, 2);
        PHASE(kt + 2, 2, 0, 1, 0, 2, 0);
        PHASE(kt + 3, 0, 1, 0, 1, 0, 1);
        PHASE(kt + 4, 1, 2, 1, 0, 1, 2);
        PHASE(kt + 5, 2, 0, 0, 1, 2, 0);
    }
    PHASE(60, 0, 1, 1, 0, 0, 1);
    PHASE(61, 1, 2, 0, 1, 1, 2);
    PHASE(62, 2, 0, 1, 0, 2, 0);
    PHASE(63, 0, 1, 0, 1, 0, 1);
#undef PHASE

    // Epilogue: x = acc + be[n] + dec[b][n]; t = tanh(x); rowsum += t*wa[n]
    float rsum[4][4];
#pragma unroll
    for (int mi = 0; mi < 4; ++mi)
#pragma unroll
        for (int j = 0; j < 4; ++j) rsum[mi][j] = 0.f;

    int nb = ntile * 128 + wn * 64;
    int rb = mtile * 128 + wm * 64;
#pragma unroll
    for (int ni = 0; ni < 4; ++ni) {
        int n = nb + ni * 16 + l15;
        float wav = wa[n];
        float bev = be[n];
#pragma unroll
        for (int mi = 0; mi < 4; ++mi) {
#pragma unroll
            for (int j = 0; j < 4; ++j) {
                int row = rb + mi * 16 + lg * 4 + j;    // C/D: col=lane&15, row=(lane>>4)*4+reg
                int b = row / L_;
                float x = acc[mi][ni][j] + bev + dec[b * ATT_ + n];
                float e = __expf(2.0f * x);
                float t = 1.0f - 2.0f / (e + 1.0f);     // tanh(x), inf-safe
                rsum[mi][j] += t * wav;
            }
        }
    }
#pragma unroll
    for (int mi = 0; mi < 4; ++mi) {
#pragma unroll
        for (int j = 0; j < 4; ++j) {
            float v = rsum[mi][j];
            v += __shfl_xor(v, 1);
            v += __shfl_xor(v, 2);
            v += __shfl_xor(v, 4);
            v += __shfl_xor(v, 8);
            if (l15 == 0) red[wn][wm * 64 + mi * 16 + lg * 4 + j] = v;
        }
    }
    __syncthreads();
    if (tid < 128)
        partial[(size_t)ntile * M_ + mtile * 128 + tid] = red[0][tid] + red[1][tid];
}

// softmax over L per batch row. ba cancels in softmax -> skipped.
__global__ void softmax_kernel(const float* __restrict__ partial, float* __restrict__ alphas) {
    int b = blockIdx.x, t = threadIdx.x;     // 128 blocks x 256 threads
    int lane = t & 63, wid = t >> 6;
    __shared__ float red[4];
    float s = 0.f, val = -1e30f;
    if (t < L_) {
        int r = b * L_ + t;
        s = partial[r] + partial[M_ + r] + partial[2 * M_ + r] + partial[3 * M_ + r];
        val = s;
    }
    float m = val;
#pragma unroll
    for (int off = 1; off < 64; off <<= 1) m = fmaxf(m, __shfl_xor(m, off));
    if (lane == 0) red[wid] = m;
    __syncthreads();
    m = fmaxf(fmaxf(red[0], red[1]), fmaxf(red[2], red[3]));
    float e = (t < L_) ? __expf(s - m) : 0.f;
    float sum = e;
#pragma unroll
    for (int off = 1; off < 64; off <<= 1) sum += __shfl_xor(sum, off);
    __syncthreads();
    if (lane == 0) red[wid] = sum;
    __syncthreads();
    sum = red[0] + red[1] + red[2] + red[3];
    if (t < L_) alphas[b * L_ + t] = e / sum;
}

// context[b][e] = sum_l alphas[b][l] * enc[b][l][e]   (memory-bound pass)
__global__ void context_kernel(const float* __restrict__ enc, const float* __restrict__ alphas,
                               float* __restrict__ ctx) {
    int b = blockIdx.x >> 2;                  // 128 b x 4 e-chunks = 512 blocks
    int ec = blockIdx.x & 3;
    int e = ec * 512 + threadIdx.x * 2;
    const float* ep = enc + (size_t)b * L_ * ENC_ + e;
    const float* ap = alphas + b * L_;
    float ax = 0.f, ay = 0.f;
#pragma unroll 4
    for (int l = 0; l < L_; ++l) {
        float a = ap[l];
        float2 v = *reinterpret_cast<const float2*>(ep + (size_t)l * ENC_);
        ax += a * v.x;
        ay += a * v.y;
    }
    float2 r; r.x = ax; r.y = ay;
    *reinterpret_cast<float2*>(&ctx[b * ENC_ + e]) = r;
}

extern "C" void kernel_launch(void* const* d_in, const int* in_sizes, int n_in,
                              void* d_out, int out_size, void* d_ws, size_t ws_size,
                              hipStream_t stream) {
    const float* enc = (const float*)d_in[0];
    const float* dh  = (const float*)d_in[1];
    const float* We  = (const float*)d_in[2];
    const float* be  = (const float*)d_in[3];
    const float* Wd  = (const float*)d_in[4];
    const float* bd  = (const float*)d_in[5];
    const float* wa  = (const float*)d_in[6];
    // d_in[7] = ba: shifts all scores equally -> cancels in softmax, unused.

    float* out    = (float*)d_out;
    float* ctx    = out;               // [128][2048]
    float* alphas = out + B_ * ENC_;   // [128][196]

    char* ws = (char*)d_ws;
    float*    dec     = (float*)ws;                            // 256 KiB
    _Float16* WeTs    = (_Float16*)(ws + 262144);              // 2 MiB
    float*    partial = (float*)(ws + 262144 + 2097152);       // 392 KiB

    hipLaunchKernelGGL(wets_kernel,       dim3(512),  dim3(256), 0, stream, We, WeTs);
    hipLaunchKernelGGL(decmap_kernel,     dim3(128),  dim3(512), 0, stream, dh, Wd, bd, dec);
    hipLaunchKernelGGL(gemm_score_kernel, dim3(784),  dim3(256), 0, stream, enc, WeTs, be, wa, dec, partial);
    hipLaunchKernelGGL(softmax_kernel,    dim3(128),  dim3(256), 0, stream, partial, alphas);
    hipLaunchKernelGGL(context_kernel,    dim3(512),  dim3(256), 0, stream, enc, alphas, ctx);
}